// Round 11
// baseline (107.977 us; speedup 1.0000x reference)
//
#include <hip/hip_runtime.h>
#include <hip/hip_bf16.h>
#include <stdint.h>

#define NBIN 240          // binning blocks (+1 consts block)
#define RSH 7
#define RNODES 128
#define SPILLCAP 16384
#define TS 68

// ---------------- helpers ----------------
__device__ __forceinline__ float bf2f(unsigned short u) {
    unsigned int x = ((unsigned int)u) << 16;
    return __uint_as_float(x);
}
__device__ __forceinline__ unsigned short f2bf(float f) {
    unsigned int x = __float_as_uint(f);
    unsigned int lsb = (x >> 16) & 1u;
    x += 0x7fffu + lsb;           // round-to-nearest-even
    return (unsigned short)(x >> 16);
}
__device__ __forceinline__ unsigned int pack2bf(float lo, float hi) {
    return (unsigned int)f2bf(lo) | ((unsigned int)f2bf(hi) << 16);
}
__device__ __forceinline__ float bflo(unsigned int u) { return __uint_as_float(u << 16); }
__device__ __forceinline__ float bfhi(unsigned int u) { return __uint_as_float(u & 0xffff0000u); }
__device__ __forceinline__ float loadF(const void* p, int i, int isbf) {
    return isbf ? bf2f(((const unsigned short*)p)[i]) : ((const float*)p)[i];
}

// ---------------- init: flags + spill cursor + sentinel z rows ----------------
// flags[0]=bf16?, flags[1]=int64?, flags[2]=spill cursor
__global__ void k_init(const void* x, const void* eidx, int* flags,
                       unsigned int* z0s, unsigned int* z1s) {
    int t = threadIdx.x;   // 128
    if (t < 8) z0s[t] = 0;
    else if (t < 16) z1s[t - 8] = 0;
    if (t == 16) flags[2] = 0;
    if (t < 64) {
        const unsigned short* u = (const unsigned short*)x;
        float a = fabsf(bf2f(u[2 * t]));
        bool ok = (a == 0.0f) || (a > 1e-30f && a < 1e4f);
        unsigned long long mbf = __ballot(ok);
        if (t == 0) flags[0] = (mbf == ~0ULL) ? 1 : 0;
    } else if (t < 128) {
        int l = t - 64;
        const int* ip = (const int*)eidx;
        unsigned long long mi64 = __ballot(ip[2 * l + 1] == 0);
        if (l == 0) flags[1] = (mi64 == ~0ULL) ? 1 : 0;
    }
}

// ---------------- fused: single-pass segmented binning + consts block ----------
// bins[(bucket*NBIN + blk)*capBB + slot] ; cnts[bucket*NBIN + blk]
// Consts (block NBIN): M = W1^3 W2 ; cvecs = {g3,g2,g1,b2}
__global__ void k_bin(const void* eidx, int E, int B, int capBB,
                      unsigned int* bins, int* cnts, int* flags, int2* spill,
                      const void* W1, const void* b1, const void* W2, const void* b2,
                      float* M, float* cvecs) {
    if ((int)blockIdx.x == NBIN) {   // ---- consts block ----
        __shared__ float A[64 * 64];
        __shared__ float T1[64 * TS];
        __shared__ float T2[64 * TS];
        __shared__ float B2s[64 * 16];
        __shared__ float bv[64], bw1[64], bw2[64];
        int bf = flags[0];
        int t = threadIdx.x;   // 512; use 256
        if (t < 256) {
            for (int i = t; i < 4096; i += 256) A[i] = loadF(W1, i, bf);
            for (int i = t; i < 1024; i += 256) B2s[i] = loadF(W2, i, bf);
            if (t < 64) bv[t] = loadF(b1, t, bf);
        }
        __syncthreads();
        if (t < 256) {
            const int i0 = (t >> 4) * 4;
            const int j0 = (t & 15) * 4;
            {   // T1 = A @ A
                float acc[4][4] = {};
#pragma unroll 8
                for (int k = 0; k < 64; ++k) {
                    float a0 = A[(i0 + 0) * 64 + k];
                    float a1 = A[(i0 + 1) * 64 + k];
                    float a2 = A[(i0 + 2) * 64 + k];
                    float a3 = A[(i0 + 3) * 64 + k];
                    float4 bq = *(const float4*)&A[k * 64 + j0];
                    acc[0][0] += a0 * bq.x; acc[0][1] += a0 * bq.y; acc[0][2] += a0 * bq.z; acc[0][3] += a0 * bq.w;
                    acc[1][0] += a1 * bq.x; acc[1][1] += a1 * bq.y; acc[1][2] += a1 * bq.z; acc[1][3] += a1 * bq.w;
                    acc[2][0] += a2 * bq.x; acc[2][1] += a2 * bq.y; acc[2][2] += a2 * bq.z; acc[2][3] += a2 * bq.w;
                    acc[3][0] += a3 * bq.x; acc[3][1] += a3 * bq.y; acc[3][2] += a3 * bq.z; acc[3][3] += a3 * bq.w;
                }
#pragma unroll
                for (int ii = 0; ii < 4; ++ii)
                    *(float4*)&T1[(i0 + ii) * TS + j0] = make_float4(acc[ii][0], acc[ii][1], acc[ii][2], acc[ii][3]);
            }
            if (t < 64) {
                float acc = 0.f;
#pragma unroll 8
                for (int i = 0; i < 64; ++i) acc += bv[i] * A[i * 64 + t];
                bw1[t] = acc;
            }
        }
        __syncthreads();
        if (t < 256) {
            const int i0 = (t >> 4) * 4;
            const int j0 = (t & 15) * 4;
            {   // T2 = T1 @ A
                float acc[4][4] = {};
#pragma unroll 8
                for (int k = 0; k < 64; ++k) {
                    float a0 = T1[(i0 + 0) * TS + k];
                    float a1 = T1[(i0 + 1) * TS + k];
                    float a2 = T1[(i0 + 2) * TS + k];
                    float a3 = T1[(i0 + 3) * TS + k];
                    float4 bq = *(const float4*)&A[k * 64 + j0];
                    acc[0][0] += a0 * bq.x; acc[0][1] += a0 * bq.y; acc[0][2] += a0 * bq.z; acc[0][3] += a0 * bq.w;
                    acc[1][0] += a1 * bq.x; acc[1][1] += a1 * bq.y; acc[1][2] += a1 * bq.z; acc[1][3] += a1 * bq.w;
                    acc[2][0] += a2 * bq.x; acc[2][1] += a2 * bq.y; acc[2][2] += a2 * bq.z; acc[2][3] += a2 * bq.w;
                    acc[3][0] += a3 * bq.x; acc[3][1] += a3 * bq.y; acc[3][2] += a3 * bq.z; acc[3][3] += a3 * bq.w;
                }
#pragma unroll
                for (int ii = 0; ii < 4; ++ii)
                    *(float4*)&T2[(i0 + ii) * TS + j0] = make_float4(acc[ii][0], acc[ii][1], acc[ii][2], acc[ii][3]);
            }
            if (t < 64) {
                float acc = 0.f;
#pragma unroll 8
                for (int i = 0; i < 64; ++i) acc += bw1[i] * A[i * 64 + t];
                bw2[t] = acc;
            }
        }
        __syncthreads();
        if (t < 256) {
            {   // M = T2 @ B2 (64x16)
                int i = t >> 2, j0m = (t & 3) * 4;
                float4 acc = {0.f, 0.f, 0.f, 0.f};
#pragma unroll 8
                for (int k = 0; k < 64; ++k) {
                    float a = T2[i * TS + k];
                    float4 bq = *(const float4*)&B2s[k * 16 + j0m];
                    acc.x += a * bq.x; acc.y += a * bq.y; acc.z += a * bq.z; acc.w += a * bq.w;
                }
                *(float4*)&M[i * 16 + j0m] = acc;
            }
            if (t < 16) {
                float a3 = 0.f, a2 = 0.f, a1 = 0.f;
#pragma unroll 8
                for (int i = 0; i < 64; ++i) {
                    float w = B2s[i * 16 + t];
                    a3 += bw2[i] * w;
                    a2 += bw1[i] * w;
                    a1 += bv[i] * w;
                }
                cvecs[t] = a3;
                cvecs[16 + t] = a2;
                cvecs[32 + t] = a1;
                cvecs[48 + t] = loadF(b2, t, flags[0]);
            }
        }
        return;
    }
    // ---- binning blocks: single pass ----
    extern __shared__ int hist[];          // B ints
    const int i64 = flags[1];
    const int t = threadIdx.x, nt = blockDim.x;
    const int blk = blockIdx.x;
    const long long i0 = (long long)blk * E / NBIN;
    const long long i1 = (long long)(blk + 1) * E / NBIN;
    const long long* e64 = (const long long*)eidx;
    const int* e32 = (const int*)eidx;
    const int mask = RNODES - 1;

    for (int b = t; b < B; b += nt) hist[b] = 0;
    __syncthreads();
    for (long long i = i0 + t; i < i1; i += nt) {
        int d, s;
        if (i64) { d = (int)e64[E + i]; s = (int)e64[i]; }
        else     { d = e32[E + i];     s = e32[i]; }
        int b = d >> RSH;
        unsigned int pk = ((unsigned int)s << RSH) | (unsigned int)(d & mask);
        int pos = atomicAdd(&hist[b], 1);
        if (pos < capBB) {
            bins[(size_t)(b * NBIN + blk) * capBB + pos] = pk;
        } else {
            int sp = atomicAdd(&flags[2], 1);
            if (sp < SPILLCAP) spill[sp] = make_int2(b, (int)pk);
        }
    }
    __syncthreads();
    for (int b = t; b < B; b += nt) {
        int c = hist[b];
        cnts[b * NBIN + blk] = c > capBB ? capBB : c;
    }
}

// ---------------- per-bucket CSR build + fused z0 = bf16(dinv * x@M) ----------
__global__ void k_csr(const unsigned int* bins, const int* cnts, int capBB,
                      const int* flags, const int2* spill,
                      int n, int* colb, int capP, int4* meta,
                      const void* x, const float* M, unsigned short* z0) {
    __shared__ int compact[2048];
    __shared__ int scnt[NBIN], sof[NBIN];
    __shared__ int dh[RNODES], db[RNODES], pl[RNODES], ch[RNODES];
    __shared__ float Ms[1024];
    __shared__ float xs[RNODES * 65];
    __shared__ int sextra;
    const int b = blockIdx.x, t = threadIdx.x, nt = blockDim.x;   // 256
    const int mask = RNODES - 1;
    // ---- A: gather segments into compact ----
    if (t < NBIN) { int c = cnts[b * NBIN + t]; scnt[t] = c > capBB ? capBB : c; }
    if (t < RNODES) { dh[t] = 0; ch[t] = 0; }
    if (t == 0) sextra = 0;
    __syncthreads();
    if (t < NBIN) sof[t] = scnt[t];
    __syncthreads();
    for (int off = 1; off < NBIN; off <<= 1) {
        int add = 0;
        if (t < NBIN && t >= off) add = sof[t - off];
        __syncthreads();
        if (t < NBIN) sof[t] += add;
        __syncthreads();
    }
    int total = sof[NBIN - 1];
    if (t < NBIN) {
        const unsigned int* seg = bins + (size_t)(b * NBIN + t) * capBB;
        int dst = sof[t] - scnt[t];
        for (int i = 0; i < scnt[t]; ++i) compact[dst + i] = (int)seg[i];
    }
    // spill merge
    {
        int scount = flags[2];
        if (scount > SPILLCAP) scount = SPILLCAP;
        for (int i = t; i < scount; i += nt) {
            int2 sp = spill[i];
            if (sp.x == b) {
                int p = atomicAdd(&sextra, 1);
                if (total + p < 2048) compact[total + p] = sp.y;
            }
        }
    }
    __syncthreads();
    {
        int ex = sextra;
        if (total + ex > 2048) ex = 2048 - total;
        total += ex;
    }
    // ---- B: histogram + scan + meta + scatter to colb ----
    for (int e = t; e < total; e += nt)
        atomicAdd(&dh[compact[e] & mask], 1);
    __syncthreads();
    if (t < RNODES) { pl[t] = (dh[t] + 3) & ~3; db[t] = pl[t]; }
    __syncthreads();
    for (int off = 1; off < RNODES; off <<= 1) {
        int add = 0;
        if (t < RNODES && t >= off) add = db[t - off];
        __syncthreads();
        if (t < RNODES) db[t] += add;
        __syncthreads();
    }
    const int v0 = b << RSH;
    const int gbase = b * capP;
    if (t < RNODES) {
        int v = v0 + t;
        if (v < n) {
            int len = dh[t];
            float dv = rsqrtf((float)(len + 1));
            int rs = gbase + db[t] - pl[t];
            meta[v] = make_int4(rs, len, __float_as_int(dv), 0);
            for (int p = len; p < pl[t]; ++p) colb[rs + p] = n;   // sentinel pad
        }
    }
    __syncthreads();
    for (int e = t; e < total; e += nt) {
        int w = compact[e];
        int r = w & mask;
        int pos = (db[r] - pl[r]) + atomicAdd(&ch[r], 1);
        colb[gbase + pos] = w >> RSH;
    }
    // ---- C: fused xm for this bucket's nodes ----
    const int bf = flags[0];
    ((float4*)Ms)[t] = ((const float4*)M)[t];
    int nvalid = n - v0;
    if (nvalid > RNODES) nvalid = RNODES;
    if (nvalid > 0) {
        if (!bf) {
            const float* xf = (const float*)x + (size_t)v0 * 64;
            for (int i = t; i < nvalid * 16; i += nt) {
                int r = i >> 4, c4 = (i & 15) * 4;
                float4 v = *(const float4*)&xf[r * 64 + c4];
                float* xp = &xs[r * 65 + c4];
                xp[0] = v.x; xp[1] = v.y; xp[2] = v.z; xp[3] = v.w;
            }
        } else {
            const unsigned short* xu = (const unsigned short*)x + (size_t)v0 * 64;
            for (int i = t; i < nvalid * 16; i += nt) {
                int r = i >> 4, c4 = (i & 15) * 4;
                ushort4 v = *(const ushort4*)&xu[r * 64 + c4];
                float* xp = &xs[r * 65 + c4];
                xp[0] = bf2f(v.x); xp[1] = bf2f(v.y); xp[2] = bf2f(v.z); xp[3] = bf2f(v.w);
            }
        }
    }
    __syncthreads();
    {
        int r = t >> 1, h = t & 1;
        int v = v0 + r;
        if (v < n) {
            float a0 = 0.f, a1 = 0.f, a2 = 0.f, a3 = 0.f;
            float a4 = 0.f, a5 = 0.f, a6 = 0.f, a7 = 0.f;
#pragma unroll 8
            for (int k = 0; k < 64; ++k) {
                float xv = xs[r * 65 + k];
                const float* mp = &Ms[k * 16 + h * 8];
                a0 += xv * mp[0]; a1 += xv * mp[1]; a2 += xv * mp[2]; a3 += xv * mp[3];
                a4 += xv * mp[4]; a5 += xv * mp[5]; a6 += xv * mp[6]; a7 += xv * mp[7];
            }
            float dv = rsqrtf((float)(dh[r] + 1));
            int4 ov;
            ov.x = (int)pack2bf(dv * a0, dv * a1);
            ov.y = (int)pack2bf(dv * a2, dv * a3);
            ov.z = (int)pack2bf(dv * a4, dv * a5);
            ov.w = (int)pack2bf(dv * a6, dv * a7);
            *(int4*)&z0[(size_t)v * 16 + h * 8] = ov;
        }
    }
}

// ---------------- pull prop: 2 lanes/node, int4 colb, 16B bf16 gathers --------
__global__ void k_prop(const unsigned short* zin, void* yout, const int4* meta,
                       const int* colb, const float* cvec,
                       int n, int is_final, const int* flags) {
    int tid = blockIdx.x * blockDim.x + threadIdx.x;
    int v = tid >> 1, h = tid & 1;         // lane h covers channels [h*8, h*8+8)
    if (v >= n) return;
    int4 m = meta[v];                      // {rstart, len, dinv_bits, 0}
    int beg = m.x, len = m.y;
    int padlen = (len + 3) & ~3;
    int4 sw = *(const int4*)&zin[(size_t)v * 16 + h * 8];
    float a0 = bflo((unsigned)sw.x), a1 = bfhi((unsigned)sw.x);
    float a2 = bflo((unsigned)sw.y), a3 = bfhi((unsigned)sw.y);
    float a4 = bflo((unsigned)sw.z), a5 = bfhi((unsigned)sw.z);
    float a6 = bflo((unsigned)sw.w), a7 = bfhi((unsigned)sw.w);
    for (int j = beg; j < beg + padlen; j += 4) {
        int4 cc = *(const int4*)&colb[j];
        int4 za = *(const int4*)&zin[(size_t)cc.x * 16 + h * 8];
        int4 zb = *(const int4*)&zin[(size_t)cc.y * 16 + h * 8];
        int4 zc = *(const int4*)&zin[(size_t)cc.z * 16 + h * 8];
        int4 zd = *(const int4*)&zin[(size_t)cc.w * 16 + h * 8];
        a0 += (bflo((unsigned)za.x) + bflo((unsigned)zb.x)) + (bflo((unsigned)zc.x) + bflo((unsigned)zd.x));
        a1 += (bfhi((unsigned)za.x) + bfhi((unsigned)zb.x)) + (bfhi((unsigned)zc.x) + bfhi((unsigned)zd.x));
        a2 += (bflo((unsigned)za.y) + bflo((unsigned)zb.y)) + (bflo((unsigned)zc.y) + bflo((unsigned)zd.y));
        a3 += (bfhi((unsigned)za.y) + bfhi((unsigned)zb.y)) + (bfhi((unsigned)zc.y) + bfhi((unsigned)zd.y));
        a4 += (bflo((unsigned)za.z) + bflo((unsigned)zb.z)) + (bflo((unsigned)zc.z) + bflo((unsigned)zd.z));
        a5 += (bfhi((unsigned)za.z) + bfhi((unsigned)zb.z)) + (bfhi((unsigned)zc.z) + bfhi((unsigned)zd.z));
        a6 += (bflo((unsigned)za.w) + bflo((unsigned)zb.w)) + (bflo((unsigned)zc.w) + bflo((unsigned)zd.w));
        a7 += (bfhi((unsigned)za.w) + bfhi((unsigned)zb.w)) + (bfhi((unsigned)zc.w) + bfhi((unsigned)zd.w));
    }
    float dv = __int_as_float(m.z);
    float sa = is_final ? dv : dv * dv;
    float sb = is_final ? 1.0f : dv;
    float4 cv0 = *(const float4*)&cvec[h * 8];
    float4 cv1 = *(const float4*)&cvec[h * 8 + 4];
    float r0 = sa * a0 + sb * cv0.x;
    float r1 = sa * a1 + sb * cv0.y;
    float r2 = sa * a2 + sb * cv0.z;
    float r3 = sa * a3 + sb * cv0.w;
    float r4 = sa * a4 + sb * cv1.x;
    float r5 = sa * a5 + sb * cv1.y;
    float r6 = sa * a6 + sb * cv1.z;
    float r7 = sa * a7 + sb * cv1.w;
    if (is_final && !flags[0]) {
        float* o = &((float*)yout)[(size_t)v * 16 + h * 8];
        *(float4*)o = make_float4(r0, r1, r2, r3);
        *(float4*)(o + 4) = make_float4(r4, r5, r6, r7);
    } else {
        int4 ov;
        ov.x = (int)pack2bf(r0, r1);
        ov.y = (int)pack2bf(r2, r3);
        ov.z = (int)pack2bf(r4, r5);
        ov.w = (int)pack2bf(r6, r7);
        *(int4*)&((unsigned short*)yout)[(size_t)v * 16 + h * 8] = ov;
    }
}

// ---------------- launch ----------------
extern "C" void kernel_launch(void* const* d_in, const int* in_sizes, int n_in,
                              void* d_out, int out_size, void* d_ws, size_t ws_size,
                              hipStream_t stream) {
    const void* x  = d_in[0];
    const void* W1 = d_in[1];
    const void* b1 = d_in[2];
    const void* W2 = d_in[3];
    const void* b2 = d_in[4];
    const void* ei = d_in[5];

    const int n = in_sizes[0] / 64;       // 100000
    const int E = in_sizes[5] / 2;        // 1000000
    const int B = (n + RNODES - 1) >> RSH;            // 782
    const int capP = 2432;                            // per-bucket colb stride

    char* base = (char*)d_ws;
    size_t off = 0;
    auto carve = [&](size_t bytes) -> void* {
        void* r = base + off;
        off = (off + bytes + 255) & ~(size_t)255;
        return r;
    };
    int*            flags = (int*)carve(16);
    int*            cnts  = (int*)carve((size_t)NBIN * B * 4);
    int2*           spill = (int2*)carve((size_t)SPILLCAP * 8);
    int*            colb  = (int*)carve((size_t)B * capP * 4);
    int4*           meta  = (int4*)carve((size_t)n * 16);
    float*          Mm    = (float*)carve(1024 * 4);
    float*          cvecs = (float*)carve(64 * 4);
    unsigned short* z0    = (unsigned short*)carve(((size_t)n + 1) * 16 * 2);
    unsigned short* z1    = (unsigned short*)carve(((size_t)n + 1) * 16 * 2);
    // bins last: capacity adaptive to remaining workspace
    size_t remain = (ws_size > off) ? (ws_size - off) : 0;
    int capBB = (int)(remain / ((size_t)NBIN * B * 4));
    if (capBB > 28) capBB = 28;
    if (capBB < 12) capBB = 12;           // ws proven >= ~29MB in prior rounds
    unsigned int* bins = (unsigned int*)carve((size_t)NBIN * B * capBB * 4);
    (void)n_in; (void)out_size;

    k_init<<<1, 128, 0, stream>>>(x, ei, flags,
                                  (unsigned int*)&z0[(size_t)n * 16],
                                  (unsigned int*)&z1[(size_t)n * 16]);
    k_bin<<<NBIN + 1, 512, (size_t)B * 4, stream>>>(ei, E, B, capBB, bins, cnts,
                                                    flags, spill,
                                                    W1, b1, W2, b2, Mm, cvecs);
    k_csr<<<B, 256, 0, stream>>>(bins, cnts, capBB, flags, spill,
                                 n, colb, capP, meta, x, Mm, z0);

    const int pgrid = (n * 2 + 255) / 256;
    k_prop<<<pgrid, 256, 0, stream>>>(z0, z1, meta, colb, cvecs + 0,  n, 0, flags);
    k_prop<<<pgrid, 256, 0, stream>>>(z1, z0, meta, colb, cvecs + 16, n, 0, flags);
    k_prop<<<pgrid, 256, 0, stream>>>(z0, z1, meta, colb, cvecs + 32, n, 0, flags);
    k_prop<<<pgrid, 256, 0, stream>>>(z1, d_out, meta, colb, cvecs + 48, n, 1, flags);
}

// Round 12
// 96.753 us; speedup vs baseline: 1.1160x; 1.1160x over previous
//
#include <hip/hip_runtime.h>
#include <hip/hip_bf16.h>
#include <stdint.h>

// ---------------- helpers ----------------
__device__ __forceinline__ float bf2f(unsigned short u) {
    unsigned int x = ((unsigned int)u) << 16;
    return __uint_as_float(x);
}
__device__ __forceinline__ unsigned short f2bf(float f) {
    unsigned int x = __float_as_uint(f);
    unsigned int lsb = (x >> 16) & 1u;
    x += 0x7fffu + lsb;           // round-to-nearest-even
    return (unsigned short)(x >> 16);
}
__device__ __forceinline__ unsigned int pack2bf(float lo, float hi) {
    return (unsigned int)f2bf(lo) | ((unsigned int)f2bf(hi) << 16);
}
__device__ __forceinline__ float loadF(const void* p, int i, int isbf) {
    return isbf ? bf2f(((const unsigned short*)p)[i]) : ((const float*)p)[i];
}

// ---------------- init: zero bcnt + dtype flags ----------------
// flags[0] = floats bf16(1)/f32(0); flags[1] = edge_index int64(1)/int32(0)
__global__ void k_init(const void* x, const void* eidx, int* flags, int* bcnt, int B) {
    int t = threadIdx.x;   // 1024
    for (int b = t; b < B; b += blockDim.x) bcnt[b] = 0;
    if (t < 64) {
        const unsigned short* u = (const unsigned short*)x;
        float a = fabsf(bf2f(u[2 * t]));
        bool ok = (a == 0.0f) || (a > 1e-30f && a < 1e4f);
        unsigned long long mbf = __ballot(ok);
        if (t == 0) flags[0] = (mbf == ~0ULL) ? 1 : 0;
    } else if (t < 128) {
        int l = t - 64;
        const int* ip = (const int*)eidx;
        unsigned long long mi64 = __ballot(ip[2 * l + 1] == 0);
        if (l == 0) flags[1] = (mi64 == ~0ULL) ? 1 : 0;
    }
}

// ---------------- fused: edge binning (blocks 0..G-1) + consts (block G) -------
// Binning: bucket = dst >> rsh (R=128). Packed word = (src << rsh) | (dst & R-1).
// Consts: M = W1^3 W2 ; cvecs = {g3=b1W1^2W2, g2=b1W1W2, g1=b1W2, b2}
#define TS 68
__global__ void k_bin(const void* eidx, int E, int rsh, int B, int cap,
                      unsigned int* bins, int* bcnt, const int* flags,
                      const void* W1, const void* b1, const void* W2, const void* b2,
                      float* M, float* cvecs, int nbin) {
    if ((int)blockIdx.x == nbin) {   // ---- consts block ----
        __shared__ float A[64 * 64];
        __shared__ float T1[64 * TS];
        __shared__ float T2[64 * TS];
        __shared__ float B2s[64 * 16];
        __shared__ float bv[64], bw1[64], bw2[64];
        int bf = flags[0];
        int t = threadIdx.x;   // 512 threads; use 256
        if (t < 256) {
            for (int i = t; i < 4096; i += 256) A[i] = loadF(W1, i, bf);
            for (int i = t; i < 1024; i += 256) B2s[i] = loadF(W2, i, bf);
            if (t < 64) bv[t] = loadF(b1, t, bf);
        }
        __syncthreads();
        if (t < 256) {
            const int i0 = (t >> 4) * 4;
            const int j0 = (t & 15) * 4;
            {   // T1 = A @ A
                float acc[4][4] = {};
#pragma unroll 8
                for (int k = 0; k < 64; ++k) {
                    float a0 = A[(i0 + 0) * 64 + k];
                    float a1 = A[(i0 + 1) * 64 + k];
                    float a2 = A[(i0 + 2) * 64 + k];
                    float a3 = A[(i0 + 3) * 64 + k];
                    float4 bq = *(const float4*)&A[k * 64 + j0];
                    acc[0][0] += a0 * bq.x; acc[0][1] += a0 * bq.y; acc[0][2] += a0 * bq.z; acc[0][3] += a0 * bq.w;
                    acc[1][0] += a1 * bq.x; acc[1][1] += a1 * bq.y; acc[1][2] += a1 * bq.z; acc[1][3] += a1 * bq.w;
                    acc[2][0] += a2 * bq.x; acc[2][1] += a2 * bq.y; acc[2][2] += a2 * bq.z; acc[2][3] += a2 * bq.w;
                    acc[3][0] += a3 * bq.x; acc[3][1] += a3 * bq.y; acc[3][2] += a3 * bq.z; acc[3][3] += a3 * bq.w;
                }
#pragma unroll
                for (int ii = 0; ii < 4; ++ii)
                    *(float4*)&T1[(i0 + ii) * TS + j0] = make_float4(acc[ii][0], acc[ii][1], acc[ii][2], acc[ii][3]);
            }
            if (t < 64) {
                float acc = 0.f;
#pragma unroll 8
                for (int i = 0; i < 64; ++i) acc += bv[i] * A[i * 64 + t];
                bw1[t] = acc;
            }
        }
        __syncthreads();
        if (t < 256) {
            const int i0 = (t >> 4) * 4;
            const int j0 = (t & 15) * 4;
            {   // T2 = T1 @ A
                float acc[4][4] = {};
#pragma unroll 8
                for (int k = 0; k < 64; ++k) {
                    float a0 = T1[(i0 + 0) * TS + k];
                    float a1 = T1[(i0 + 1) * TS + k];
                    float a2 = T1[(i0 + 2) * TS + k];
                    float a3 = T1[(i0 + 3) * TS + k];
                    float4 bq = *(const float4*)&A[k * 64 + j0];
                    acc[0][0] += a0 * bq.x; acc[0][1] += a0 * bq.y; acc[0][2] += a0 * bq.z; acc[0][3] += a0 * bq.w;
                    acc[1][0] += a1 * bq.x; acc[1][1] += a1 * bq.y; acc[1][2] += a1 * bq.z; acc[1][3] += a1 * bq.w;
                    acc[2][0] += a2 * bq.x; acc[2][1] += a2 * bq.y; acc[2][2] += a2 * bq.z; acc[2][3] += a2 * bq.w;
                    acc[3][0] += a3 * bq.x; acc[3][1] += a3 * bq.y; acc[3][2] += a3 * bq.z; acc[3][3] += a3 * bq.w;
                }
#pragma unroll
                for (int ii = 0; ii < 4; ++ii)
                    *(float4*)&T2[(i0 + ii) * TS + j0] = make_float4(acc[ii][0], acc[ii][1], acc[ii][2], acc[ii][3]);
            }
            if (t < 64) {
                float acc = 0.f;
#pragma unroll 8
                for (int i = 0; i < 64; ++i) acc += bw1[i] * A[i * 64 + t];
                bw2[t] = acc;
            }
        }
        __syncthreads();
        if (t < 256) {
            {   // M = T2 @ B2 (64x16)
                int i = t >> 2, j0m = (t & 3) * 4;
                float4 acc = {0.f, 0.f, 0.f, 0.f};
#pragma unroll 8
                for (int k = 0; k < 64; ++k) {
                    float a = T2[i * TS + k];
                    float4 bq = *(const float4*)&B2s[k * 16 + j0m];
                    acc.x += a * bq.x; acc.y += a * bq.y; acc.z += a * bq.z; acc.w += a * bq.w;
                }
                *(float4*)&M[i * 16 + j0m] = acc;
            }
            if (t < 16) {
                float a3 = 0.f, a2 = 0.f, a1 = 0.f;
#pragma unroll 8
                for (int i = 0; i < 64; ++i) {
                    float w = B2s[i * 16 + t];
                    a3 += bw2[i] * w;
                    a2 += bw1[i] * w;
                    a1 += bv[i] * w;
                }
                cvecs[t] = a3;
                cvecs[16 + t] = a2;
                cvecs[32 + t] = a1;
                cvecs[48 + t] = loadF(b2, t, flags[0]);
            }
        }
        return;
    }
    // ---- binning blocks ----
    extern __shared__ int sh[];            // 2*B ints
    int* hist   = sh;
    int* base_s = sh + B;
    const int i64 = flags[1];
    const int t = threadIdx.x, nt = blockDim.x;
    const long long i0 = (long long)blockIdx.x * E / nbin;
    const long long i1 = (long long)(blockIdx.x + 1) * E / nbin;
    const long long* e64 = (const long long*)eidx;
    const int* e32 = (const int*)eidx;
    const int mask = (1 << rsh) - 1;

    for (int b = t; b < B; b += nt) hist[b] = 0;
    __syncthreads();
    for (long long i = i0 + t; i < i1; i += nt) {
        int d = i64 ? (int)e64[E + i] : e32[E + i];
        atomicAdd(&hist[d >> rsh], 1);
    }
    __syncthreads();
    for (int b = t; b < B; b += nt) {
        int c = hist[b];
        base_s[b] = c ? atomicAdd(&bcnt[b], c) : 0;
        hist[b] = 0;
    }
    __syncthreads();
    for (long long i = i0 + t; i < i1; i += nt) {
        int d, s;
        if (i64) { d = (int)e64[E + i]; s = (int)e64[i]; }
        else     { d = e32[E + i];     s = e32[i]; }
        int b = d >> rsh;
        int pos = base_s[b] + atomicAdd(&hist[b], 1);
        if (pos >= cap) pos = cap - 1;     // paranoia guard
        bins[(size_t)b * cap + pos] = ((unsigned int)s << rsh) | (unsigned int)(d & mask);
    }
}

// ---------------- per-bucket CSR build + fused z0 = bf16(dinv * x@M) ----------
// meta[v] = { rstart, len, dinv_bits, 0 }
__global__ void k_csr(const unsigned int* bins, const int* bcnt, int cap, int rsh,
                      int n, int* colb, int4* meta,
                      const void* x, const float* M, unsigned short* z0,
                      const int* flags) {
    __shared__ int dh[128], db[128], ch[128];
    __shared__ float Ms[1024];
    __shared__ float xs[128 * 65];
    const int R = 1 << rsh;                // 128
    const int b = blockIdx.x, t = threadIdx.x, nt = blockDim.x;   // 256
    const int mask = R - 1;
    for (int r = t; r < R; r += nt) { dh[r] = 0; ch[r] = 0; }
    __syncthreads();
    int cnt = bcnt[b]; if (cnt > cap) cnt = cap;
    const unsigned int* eb = bins + (size_t)b * cap;
    for (int e = t; e < cnt; e += nt)
        atomicAdd(&dh[eb[e] & mask], 1);
    __syncthreads();
    if (t < R) db[t] = dh[t];
    __syncthreads();
    for (int off = 1; off < R; off <<= 1) {
        int add = 0;
        if (t < R && t >= off) add = db[t - off];
        __syncthreads();
        if (t < R) db[t] += add;
        __syncthreads();
    }
    const int v0 = b << rsh;
    const int gbase = b * cap;
    if (t < R) {
        int v = v0 + t;
        if (v < n) {
            int len = dh[t];
            float dv = rsqrtf((float)(len + 1));
            meta[v] = make_int4(gbase + db[t] - len, len, __float_as_int(dv), 0);
        }
    }
    __syncthreads();
    for (int e = t; e < cnt; e += nt) {
        unsigned int w = eb[e];
        int r = w & mask;
        int pos = (db[r] - dh[r]) + atomicAdd(&ch[r], 1);
        colb[gbase + pos] = (int)(w >> rsh);
    }
    // ---- fused xm: z0[v] = bf16(dinv * (x[v] @ M)) for this bucket ----
    const int bf = flags[0];
    ((float4*)Ms)[t] = ((const float4*)M)[t];
    int nvalid = n - v0;
    if (nvalid > R) nvalid = R;
    if (nvalid > 0) {
        if (!bf) {
            const float* xf = (const float*)x + (size_t)v0 * 64;
            for (int i = t; i < nvalid * 16; i += nt) {
                int r = i >> 4, c4 = (i & 15) * 4;
                float4 v = *(const float4*)&xf[r * 64 + c4];
                float* xp = &xs[r * 65 + c4];
                xp[0] = v.x; xp[1] = v.y; xp[2] = v.z; xp[3] = v.w;
            }
        } else {
            const unsigned short* xu = (const unsigned short*)x + (size_t)v0 * 64;
            for (int i = t; i < nvalid * 16; i += nt) {
                int r = i >> 4, c4 = (i & 15) * 4;
                ushort4 v = *(const ushort4*)&xu[r * 64 + c4];
                float* xp = &xs[r * 65 + c4];
                xp[0] = bf2f(v.x); xp[1] = bf2f(v.y); xp[2] = bf2f(v.z); xp[3] = bf2f(v.w);
            }
        }
    }
    __syncthreads();
    {
        int r = t >> 1, h = t & 1;         // 2 threads per row, 8 channels each
        int v = v0 + r;
        if (v < n) {
            float a0 = 0.f, a1 = 0.f, a2 = 0.f, a3 = 0.f;
            float a4 = 0.f, a5 = 0.f, a6 = 0.f, a7 = 0.f;
#pragma unroll 8
            for (int k = 0; k < 64; ++k) {
                float xv = xs[r * 65 + k];
                const float* mp = &Ms[k * 16 + h * 8];
                a0 += xv * mp[0]; a1 += xv * mp[1]; a2 += xv * mp[2]; a3 += xv * mp[3];
                a4 += xv * mp[4]; a5 += xv * mp[5]; a6 += xv * mp[6]; a7 += xv * mp[7];
            }
            float dv = rsqrtf((float)(dh[r] + 1));
            int4 ov;
            ov.x = (int)pack2bf(dv * a0, dv * a1);
            ov.y = (int)pack2bf(dv * a2, dv * a3);
            ov.z = (int)pack2bf(dv * a4, dv * a5);
            ov.w = (int)pack2bf(dv * a6, dv * a7);
            *(int4*)&z0[(size_t)v * 16 + h * 8] = ov;
        }
    }
}

// ---------------- pull propagation: bf16 z, packed meta, 4 lanes/node ---------
// sum = z[v] + sum_{s in N(v)} z[s]
// non-final: zout = bf16(dinv^2*sum + dinv*cvec) ; final: yout = dinv*sum + cvec
__global__ void k_prop(const unsigned short* zin, void* yout, const int4* meta,
                       const int* colb, const float* cvec,
                       int n, int is_final, const int* flags) {
    int tid = blockIdx.x * blockDim.x + threadIdx.x;
    int v = tid >> 2, q = tid & 3;
    if (v >= n) return;
    int4 m = meta[v];                      // {rstart, len, dinv_bits, 0}
    int beg = m.x, len = m.y;
    ushort4 sv = *(const ushort4*)&zin[(size_t)v * 16 + q * 4];   // self-loop
    float4 acc = make_float4(bf2f(sv.x), bf2f(sv.y), bf2f(sv.z), bf2f(sv.w));
    int j = beg, end = beg + len;
    for (; j + 4 <= end; j += 4) {         // 4 gathers in flight
        int c0 = colb[j], c1 = colb[j + 1], c2 = colb[j + 2], c3 = colb[j + 3];
        ushort4 za = *(const ushort4*)&zin[(size_t)c0 * 16 + q * 4];
        ushort4 zb = *(const ushort4*)&zin[(size_t)c1 * 16 + q * 4];
        ushort4 zc = *(const ushort4*)&zin[(size_t)c2 * 16 + q * 4];
        ushort4 zd = *(const ushort4*)&zin[(size_t)c3 * 16 + q * 4];
        acc.x += (bf2f(za.x) + bf2f(zb.x)) + (bf2f(zc.x) + bf2f(zd.x));
        acc.y += (bf2f(za.y) + bf2f(zb.y)) + (bf2f(zc.y) + bf2f(zd.y));
        acc.z += (bf2f(za.z) + bf2f(zb.z)) + (bf2f(zc.z) + bf2f(zd.z));
        acc.w += (bf2f(za.w) + bf2f(zb.w)) + (bf2f(zc.w) + bf2f(zd.w));
    }
    for (; j < end; ++j) {
        int c0 = colb[j];
        ushort4 za = *(const ushort4*)&zin[(size_t)c0 * 16 + q * 4];
        acc.x += bf2f(za.x); acc.y += bf2f(za.y); acc.z += bf2f(za.z); acc.w += bf2f(za.w);
    }
    float dv = __int_as_float(m.z);
    float a = is_final ? dv : dv * dv;
    float b = is_final ? 1.0f : dv;
    float4 cv = *(const float4*)&cvec[q * 4];
    float4 val;
    val.x = a * acc.x + b * cv.x;
    val.y = a * acc.y + b * cv.y;
    val.z = a * acc.z + b * cv.z;
    val.w = a * acc.w + b * cv.w;
    int o = v * 16 + q * 4;
    if (is_final && !flags[0]) {
        *(float4*)&((float*)yout)[o] = val;
    } else {
        ushort4 ov;
        ov.x = f2bf(val.x); ov.y = f2bf(val.y); ov.z = f2bf(val.z); ov.w = f2bf(val.w);
        *(ushort4*)&((unsigned short*)yout)[o] = ov;
    }
}

// ---------------- launch ----------------
extern "C" void kernel_launch(void* const* d_in, const int* in_sizes, int n_in,
                              void* d_out, int out_size, void* d_ws, size_t ws_size,
                              hipStream_t stream) {
    const void* x  = d_in[0];
    const void* W1 = d_in[1];
    const void* b1 = d_in[2];
    const void* W2 = d_in[3];
    const void* b2 = d_in[4];
    const void* ei = d_in[5];

    const int n = in_sizes[0] / 64;       // 100000
    const int E = in_sizes[5] / 2;        // 1000000

    const int rsh = 7;
    const int B = (n + (1 << rsh) - 1) >> rsh;       // 782
    const int avg = E / B;
    int cap = avg + avg / 4 + 128;                    // mean + ~12 sigma slack
    cap = (cap + 31) & ~31;

    char* base = (char*)d_ws;
    size_t off = 0;
    auto carve = [&](size_t bytes) -> void* {
        void* r = base + off;
        off = (off + bytes + 255) & ~(size_t)255;
        return r;
    };
    int*            flags  = (int*)carve(8);
    int*            bcnt   = (int*)carve((size_t)B * 4);
    unsigned int*   bins   = (unsigned int*)carve((size_t)B * cap * 4);
    int*            colb   = (int*)carve((size_t)B * cap * 4);
    int4*           meta   = (int4*)carve((size_t)n * 16);
    float*          Mm     = (float*)carve(1024 * 4);
    float*          cvecs  = (float*)carve(64 * 4);
    unsigned short* z0     = (unsigned short*)carve((size_t)n * 16 * 2);
    unsigned short* z1     = (unsigned short*)carve((size_t)n * 16 * 2);
    (void)ws_size; (void)n_in; (void)out_size;

    const int nbin = 240;
    k_init<<<1, 1024, 0, stream>>>(x, ei, flags, bcnt, B);
    k_bin<<<nbin + 1, 512, (size_t)2 * B * 4, stream>>>(ei, E, rsh, B, cap, bins, bcnt,
                                                        flags, W1, b1, W2, b2, Mm, cvecs, nbin);
    k_csr<<<B, 256, 0, stream>>>(bins, bcnt, cap, rsh, n, colb, meta, x, Mm, z0, flags);

    const int pgrid = (n * 4 + 255) / 256;
    k_prop<<<pgrid, 256, 0, stream>>>(z0, z1, meta, colb, cvecs + 0,  n, 0, flags);
    k_prop<<<pgrid, 256, 0, stream>>>(z1, z0, meta, colb, cvecs + 16, n, 0, flags);
    k_prop<<<pgrid, 256, 0, stream>>>(z0, z1, meta, colb, cvecs + 32, n, 0, flags);
    k_prop<<<pgrid, 256, 0, stream>>>(z1, d_out, meta, colb, cvecs + 48, n, 1, flags);
}